// Round 1
// baseline (105.646 us; speedup 1.0000x reference)
//
#include <hip/hip_runtime.h>

// Retention forward, chunkwise-linear, 2 stream-ordered kernels.
//   A (ret_p12): per (bh, group-of-4-chunks) block: U_c via MFMA, group-local
//      scan in REGISTERS -> writes local prefixes L_c (c_loc=1..3) and group
//      totals T_g (g<7), bf16. Replaces old p1 (U round-trip) + p2 (serial scan).
//   B (ret_p3): S_c = L_c + sum_{g'<g} lamC^(c-4g'-4) T_g'  (<=7 terms, L2-hot),
//      then intra + cross exactly as before. Epilogue vectorized via LDS bounce.
// Measured design rules: grid.sync ~430us @1024 blocks (r4) — never.
// Per-block prefix re-scan = quadratic U traffic (+45us, r5) — never.
// bf16 intermediates verified well inside tolerance (threshold 4.46, absmax 1.0).

#define S_LEN 2048
#define DHEAD 64
#define CHUNK 64
#define NC    32
#define BH    32
#define LDK   72

typedef float  f32x4  __attribute__((ext_vector_type(4)));
typedef short  bf16x8 __attribute__((ext_vector_type(8)));
typedef unsigned short u16x8 __attribute__((ext_vector_type(8)));
typedef unsigned short u16x4 __attribute__((ext_vector_type(4)));

static __device__ __forceinline__ unsigned short f2bf(float f) {
    unsigned int u = __float_as_uint(f);
    u += 0x7FFFu + ((u >> 16) & 1u);
    return (unsigned short)(u >> 16);
}
static __device__ __forceinline__ float bf2f(unsigned short h) {
    return __uint_as_float((unsigned int)h << 16);
}

// ---------------- Kernel A: fused per-group KV summaries + register scan ----------------
// grid (8 groups, 32 bh), 256 threads. 1 block/CU. Software-pipelined chunk loads.
__global__ __launch_bounds__(256)
void ret_p12(const float* __restrict__ kg, const float* __restrict__ vg,
             unsigned short* __restrict__ Lg, unsigned short* __restrict__ Tg) {
    const int g  = (int)blockIdx.x, bh = (int)blockIdx.y, h = bh & 15;
    const int tid = (int)threadIdx.x;
    const int wv = tid >> 6, ln = tid & 63, quad = ln >> 4, lnlo = ln & 15;
    const float sh   = log2f(1.0f - exp2f(-5.0f - (float)h));   // < 0
    const float lamC = exp2f(sh * (float)CHUNK);

    __shared__ __align__(16) unsigned short Kt[CHUNK * LDK];  // lam-weighted K^T [d][j]
    __shared__ __align__(16) unsigned short Vt[CHUNK * LDK];  // V^T [e][j]

    const size_t bb = (size_t)bh * S_LEN * DHEAD;

    // fp32 register staging for the current/next chunk (prefetch pipeline)
    float rk[2][8], rv[2][8];
    {
        const size_t cb = bb + (size_t)(4 * g) * CHUNK * DHEAD;
#pragma unroll
        for (int i2 = 0; i2 < 2; ++i2) {
            const int pos0 = wv * 8 + i2 * 32;
            const float* pK = kg + cb + (size_t)pos0 * DHEAD + ln;
            const float* pV = vg + cb + (size_t)pos0 * DHEAD + ln;
#pragma unroll
            for (int j = 0; j < 8; ++j) {
                rk[i2][j] = pK[(size_t)j * DHEAD];
                rv[i2][j] = pV[(size_t)j * DHEAD];
            }
        }
    }

    f32x4 Sreg[4];  // group-local scan state, U^T fragment layout [nt]: e=nt*16+lnlo, d=wv*16+quad*4+r
#pragma unroll
    for (int nt = 0; nt < 4; ++nt) Sreg[nt] = (f32x4){0.f, 0.f, 0.f, 0.f};

    for (int i = 0; i < 4; ++i) {
        const int c = 4 * g + i;
        if (i) {  // L_c = state BEFORE chunk c (group-local); c_loc==0 implied zero, not stored
            unsigned short* lp = Lg + ((size_t)(bh * NC + c) << 12);
#pragma unroll
            for (int nt = 0; nt < 4; ++nt) {
                u16x4 w;
#pragma unroll
                for (int r = 0; r < 4; ++r) w[r] = f2bf(Sreg[nt][r]);
                *(u16x4*)&lp[(nt * 16 + lnlo) * 64 + wv * 16 + quad * 4] = w;
            }
        }
        if (g == 7 && i == 3) break;  // U_31 never consumed

        // stage (weighted K^T, V^T) from regs into LDS
#pragma unroll
        for (int i2 = 0; i2 < 2; ++i2) {
            const int pos0 = wv * 8 + i2 * 32;
            u16x8 tk, tv;
#pragma unroll
            for (int j = 0; j < 8; ++j) {
                const float w = exp2f(sh * (float)(CHUNK - pos0 - j));  // lam^(C - j_local)
                tk[j] = f2bf(rk[i2][j] * w);
                tv[j] = f2bf(rv[i2][j]);
            }
            *(u16x8*)&Kt[ln * LDK + pos0] = tk;
            *(u16x8*)&Vt[ln * LDK + pos0] = tv;
        }
        __syncthreads();

        // prefetch next chunk's K/V while this chunk's MFMAs run (skip chunk 31)
        if (i < 3 && !(g == 7 && i == 2)) {
            const size_t cb = bb + (size_t)(c + 1) * CHUNK * DHEAD;
#pragma unroll
            for (int i2 = 0; i2 < 2; ++i2) {
                const int pos0 = wv * 8 + i2 * 32;
                const float* pK = kg + cb + (size_t)pos0 * DHEAD + ln;
                const float* pV = vg + cb + (size_t)pos0 * DHEAD + ln;
#pragma unroll
                for (int j = 0; j < 8; ++j) {
                    rk[i2][j] = pK[(size_t)j * DHEAD];
                    rv[i2][j] = pV[(size_t)j * DHEAD];
                }
            }
        }

        bf16x8 aK[2];
#pragma unroll
        for (int ks = 0; ks < 2; ++ks)
            aK[ks] = *(const bf16x8*)&Kt[(wv * 16 + lnlo) * LDK + ks * 32 + quad * 8];
#pragma unroll
        for (int nt = 0; nt < 4; ++nt) {
            f32x4 acc = (f32x4){0.f, 0.f, 0.f, 0.f};
#pragma unroll
            for (int ks = 0; ks < 2; ++ks) {
                const bf16x8 bv = *(const bf16x8*)&Vt[(nt * 16 + lnlo) * LDK + ks * 32 + quad * 8];
                acc = __builtin_amdgcn_mfma_f32_16x16x32_bf16(aK[ks], bv, acc, 0, 0, 0);
            }
#pragma unroll
            for (int r = 0; r < 4; ++r) Sreg[nt][r] = lamC * Sreg[nt][r] + acc[r];
        }
        __syncthreads();  // all waves done reading LDS before next stage overwrites
    }

    if (g < 7) {  // group total T_g = sum_{j=0..3} lamC^(3-j) U_{4g+j}
        unsigned short* tp = Tg + ((size_t)(bh * 8 + g) << 12);
#pragma unroll
        for (int nt = 0; nt < 4; ++nt) {
            u16x4 w;
#pragma unroll
            for (int r = 0; r < 4; ++r) w[r] = f2bf(Sreg[nt][r]);
            *(u16x4*)&tp[(nt * 16 + lnlo) * 64 + wv * 16 + quad * 4] = w;
        }
    }
}

// ---------------- Kernel B: intra + cross (with on-the-fly S reconstruction) ----------------
__global__ __launch_bounds__(256)
void ret_p3(const float* __restrict__ qg, const float* __restrict__ kg,
            const float* __restrict__ vg, const unsigned short* __restrict__ Lg,
            const unsigned short* __restrict__ Tg, float* __restrict__ og) {
    const int c  = (int)blockIdx.x, bh = (int)blockIdx.y, h = bh & 15;
    const int tid = (int)threadIdx.x;
    const int wv = tid >> 6, ln = tid & 63, quad = ln >> 4, lnlo = ln & 15;
    const float sh    = log2f(1.0f - exp2f(-5.0f - (float)h));
    const float scale = 0.125f;

    __shared__ __align__(16) unsigned short smem[3 * CHUNK * LDK];
    unsigned short* const Ks  = smem;                  // K [pos][d]
    unsigned short* const Vt  = smem + CHUNK * LDK;    // V^T [e][pos]
    unsigned short* const ShL = smem + 2 * CHUNK * LDK;// S^T [e][d]; reused as Ws

    const size_t cb = (size_t)bh * S_LEN * DHEAD + (size_t)c * CHUNK * DHEAD;
    const float* qp = qg + cb;
    const float* kp = kg + cb;
    const float* vp = vg + cb;
    float*       op = og + cb;

    // ---- stage K [pos][d] ----
    {
        const int kr = tid >> 2, kc0 = (tid & 3) * 16;
        const float* p = kp + (size_t)kr * DHEAD + kc0;
        const f32x4 x0 = *(const f32x4*)(p + 0);
        const f32x4 x1 = *(const f32x4*)(p + 4);
        const f32x4 x2 = *(const f32x4*)(p + 8);
        const f32x4 x3 = *(const f32x4*)(p + 12);
        u16x8 w0, w1;
        w0[0]=f2bf(x0[0]); w0[1]=f2bf(x0[1]); w0[2]=f2bf(x0[2]); w0[3]=f2bf(x0[3]);
        w0[4]=f2bf(x1[0]); w0[5]=f2bf(x1[1]); w0[6]=f2bf(x1[2]); w0[7]=f2bf(x1[3]);
        w1[0]=f2bf(x2[0]); w1[1]=f2bf(x2[1]); w1[2]=f2bf(x2[2]); w1[3]=f2bf(x2[3]);
        w1[4]=f2bf(x3[0]); w1[5]=f2bf(x3[1]); w1[6]=f2bf(x3[2]); w1[7]=f2bf(x3[3]);
        *(u16x8*)&Ks[kr * LDK + kc0]     = w0;
        *(u16x8*)&Ks[kr * LDK + kc0 + 8] = w1;
    }
    // ---- stage V^T [e][pos] ----
#pragma unroll
    for (int i = 0; i < 2; ++i) {
        const int pos0 = wv * 8 + i * 32;
        const float* p = vp + (size_t)pos0 * DHEAD + ln;
        u16x8 t;
#pragma unroll
        for (int j = 0; j < 8; ++j) t[j] = f2bf(p[(size_t)j * DHEAD]);
        *(u16x8*)&Vt[ln * LDK + pos0] = t;
    }
    // ---- stage S^T = L_c + sum_{g'<g} lamC^(c-4g'-4) T_g'  (T tiles are L2-hot) ----
    {
        const int g = c >> 2;
        const int r = tid >> 2, ccol = (tid & 3) * 16;
        float accS[16];
        if (c & 3) {
            const unsigned short* lp = Lg + ((size_t)(bh * NC + c) << 12) + (size_t)tid * 16;
            const u16x8 a0 = *(const u16x8*)lp;
            const u16x8 a1 = *(const u16x8*)(lp + 8);
#pragma unroll
            for (int j = 0; j < 8; ++j) { accS[j] = bf2f(a0[j]); accS[8 + j] = bf2f(a1[j]); }
        } else {
#pragma unroll
            for (int j = 0; j < 16; ++j) accS[j] = 0.f;
        }
        for (int gp = 0; gp < g; ++gp) {   // block-uniform trip count
            const float w = exp2f(sh * (float)(CHUNK * (c - 4 * gp - 4)));
            const unsigned short* tp = Tg + ((size_t)(bh * 8 + gp) << 12) + (size_t)tid * 16;
            const u16x8 t0 = *(const u16x8*)tp;
            const u16x8 t1 = *(const u16x8*)(tp + 8);
#pragma unroll
            for (int j = 0; j < 8; ++j) { accS[j] += w * bf2f(t0[j]); accS[8 + j] += w * bf2f(t1[j]); }
        }
        u16x8 w0, w1;
#pragma unroll
        for (int j = 0; j < 8; ++j) { w0[j] = f2bf(accS[j]); w1[j] = f2bf(accS[8 + j]); }
        *(u16x8*)&ShL[r * LDK + ccol]     = w0;
        *(u16x8*)&ShL[r * LDK + ccol + 8] = w1;
    }

    // ---- Q A-fragments ----
    bf16x8 aQ[2];
    {
        const float* qrow = qp + (size_t)(wv * 16 + lnlo) * DHEAD;
#pragma unroll
        for (int ks = 0; ks < 2; ++ks) {
            const float* p = qrow + ks * 32 + quad * 8;
            bf16x8 a;
#pragma unroll
            for (int j = 0; j < 8; ++j) a[j] = (short)f2bf(p[j]);
            aQ[ks] = a;
        }
    }
    float rf[4];
#pragma unroll
    for (int r = 0; r < 4; ++r) rf[r] = exp2f((float)(wv * 16 + quad * 4 + r) * sh);

    __syncthreads();

    // ---- cross: o = Q.S ----
    f32x4 o[4];
#pragma unroll
    for (int nt = 0; nt < 4; ++nt) {
        f32x4 a = (f32x4){0.f, 0.f, 0.f, 0.f};
#pragma unroll
        for (int ks = 0; ks < 2; ++ks) {
            const bf16x8 bs = *(const bf16x8*)&ShL[(nt * 16 + lnlo) * LDK + ks * 32 + quad * 8];
            a = __builtin_amdgcn_mfma_f32_16x16x32_bf16(aQ[ks], bs, a, 0, 0, 0);
        }
        o[nt] = a;
    }

    // ---- intra scores ----
    f32x4 acc[4];
#pragma unroll
    for (int nt = 0; nt < 4; ++nt) {
        f32x4 a = (f32x4){0.f, 0.f, 0.f, 0.f};
#pragma unroll
        for (int ks = 0; ks < 2; ++ks) {
            const bf16x8 bk = *(const bf16x8*)&Ks[(nt * 16 + lnlo) * LDK + ks * 32 + quad * 8];
            a = __builtin_amdgcn_mfma_f32_16x16x32_bf16(aQ[ks], bk, a, 0, 0, 0);
        }
        acc[nt] = a;
    }

    // scale cross by scale * lam^(i_local)
#pragma unroll
    for (int nt = 0; nt < 4; ++nt)
#pragma unroll
        for (int r = 0; r < 4; ++r) o[nt][r] *= rf[r] * scale;

    __syncthreads();   // all waves done reading ShL before it becomes Ws

    // ---- decay*scale*causal; C-layout -> A-layout via LDS (same-wave RAW, no barrier) ----
#pragma unroll
    for (int nt = 0; nt < 4; ++nt) {
        const int jn = nt * 16 + lnlo;
        const float cf = scale * exp2f(-(float)jn * sh);
#pragma unroll
        for (int r = 0; r < 4; ++r) {
            const int ri = wv * 16 + quad * 4 + r;
            float wgt = acc[nt][r] * rf[r] * cf;
            if (ri < jn) wgt = 0.0f;
            ShL[ri * LDK + jn] = f2bf(wgt);
        }
    }
    const bf16x8 aW0 = *(const bf16x8*)&ShL[(wv * 16 + lnlo) * LDK + quad * 8];
    const bf16x8 aW1 = *(const bf16x8*)&ShL[(wv * 16 + lnlo) * LDK + 32 + quad * 8];

    // ---- O += P V ----
#pragma unroll
    for (int nt = 0; nt < 4; ++nt) {
        const bf16x8 bv0 = *(const bf16x8*)&Vt[(nt * 16 + lnlo) * LDK + quad * 8];
        const bf16x8 bv1 = *(const bf16x8*)&Vt[(nt * 16 + lnlo) * LDK + 32 + quad * 8];
        o[nt] = __builtin_amdgcn_mfma_f32_16x16x32_bf16(aW0, bv0, o[nt], 0, 0, 0);
        o[nt] = __builtin_amdgcn_mfma_f32_16x16x32_bf16(aW1, bv1, o[nt], 0, 0, 0);
    }

    // ---- epilogue: bounce through LDS (Ks/Vt dead) -> 4x dwordx4 coalesced stores ----
    __syncthreads();   // all waves done with Ks/Vt MFMAs before overlay
    float* const Of = (float*)smem;   // 64 x 68 fp32 = 17408 B (< Ks+Vt = 18432 B)
#pragma unroll
    for (int nt = 0; nt < 4; ++nt)
#pragma unroll
        for (int r = 0; r < 4; ++r)
            Of[(wv * 16 + quad * 4 + r) * 68 + nt * 16 + lnlo] = o[nt][r];
    // rows [wv*16, wv*16+16) written and read by the same wave -> no barrier needed
    {
        const int row = tid >> 2, col0 = (tid & 3) * 16;
        const float* src = &Of[row * 68 + col0];
        float* dst = op + (size_t)row * DHEAD + col0;
        *(f32x4*)(dst + 0)  = *(const f32x4*)(src + 0);
        *(f32x4*)(dst + 4)  = *(const f32x4*)(src + 4);
        *(f32x4*)(dst + 8)  = *(const f32x4*)(src + 8);
        *(f32x4*)(dst + 12) = *(const f32x4*)(src + 12);
    }
}

extern "C" void kernel_launch(void* const* d_in, const int* in_sizes, int n_in,
                              void* d_out, int out_size, void* d_ws, size_t ws_size,
                              hipStream_t stream) {
    (void)in_sizes; (void)n_in; (void)out_size; (void)ws_size;
    const float* q = (const float*)d_in[0];
    const float* k = (const float*)d_in[1];
    const float* v = (const float*)d_in[2];
    float* o  = (float*)d_out;
    unsigned short* Lg = (unsigned short*)d_ws;                              // 8 MB bf16 local prefixes
    unsigned short* Tg = (unsigned short*)((char*)d_ws + (16u << 20));       // 2 MB bf16 group totals

    dim3 blk(256, 1, 1);
    ret_p12<<<dim3(8, BH, 1), blk, 0, stream>>>(k, v, Lg, Tg);
    ret_p3<<<dim3(NC, BH, 1), blk, 0, stream>>>(q, k, v, Lg, Tg, o);
}